// Round 18
// baseline (250.891 us; speedup 1.0000x reference)
//
#include <hip/hip_runtime.h>

// MoE top-2 of 8 experts. B=4,S=2048,D=1024,H=1024,E=8,G=256. N=8192 tokens.
// Outputs: out[8192][1024] fp32, then loss scalar (out_size = 8388609).

#define N_TOK 8192
#define DIM   1024
#define HID   1024
#define NEXP  8
#define GDIM  256
#define NPAIR (N_TOK * 2)
#define HB_ROWS (NPAIR + 256)   // packed pair rows + read-slack (tiles read <=255 past end)
#define MT2   72                // >= sum_e ceil(cnt_e/256); 72 = 8*9
#define GAP_P 2e-3f             // xl dropped -> logit err sigma~3e-4; 6-sigma cover
#define SPLIT_SCALE 2048.0f     // W lo-residual scaling

typedef __attribute__((ext_vector_type(4))) float    f32x4;
typedef __attribute__((ext_vector_type(8))) _Float16 f16x8;
typedef __attribute__((ext_vector_type(4))) _Float16 f16x4;

static __device__ __forceinline__ void async_ld16(const void* g, void* l) {
  __builtin_amdgcn_global_load_lds(
      (const __attribute__((address_space(1))) unsigned int*)g,
      (__attribute__((address_space(3))) unsigned int*)l, 16, 0, 0);
}

// ---- prep1: split Wg1^T (hi/lo), zero ws header. 65 blocks (~3 us). ----
__global__ __launch_bounds__(256) void prep1_kernel(const float* __restrict__ Wg1,
                                                    _Float16* __restrict__ WhT,
                                                    _Float16* __restrict__ WlT,
                                                    int* __restrict__ hdr) {
  __shared__ float t[64][65];
  int bx = blockIdx.x;
  int tid = threadIdx.x;
  if (bx < 64) {
    int k0 = (bx & 15) * 64, g0 = (bx >> 4) * 64;
    int col4 = tid & 15, ib = tid >> 4;
#pragma unroll
    for (int q = 0; q < 4; ++q) {
      int i = ib * 4 + q;
      *(float4*)&t[i][col4 * 4] = *(const float4*)&Wg1[(size_t)(k0 + i) * GDIM + g0 + col4 * 4];
    }
    __syncthreads();
#pragma unroll
    for (int q = 0; q < 2; ++q) {
      int c = tid * 2 + q;
      int j = c >> 3, i8 = (c & 7) * 8;
      f16x8 h, l;
#pragma unroll
      for (int k = 0; k < 8; ++k) {
        float v = t[i8 + k][j];
        _Float16 hi = (_Float16)v;
        h[k] = hi;
        l[k] = (_Float16)((v - (float)hi) * SPLIT_SCALE);
      }
      *(f16x8*)&WhT[(size_t)(g0 + j) * DIM + k0 + i8] = h;
      *(f16x8*)&WlT[(size_t)(g0 + j) * DIM + k0 + i8] = l;
    }
  } else {
    hdr[tid * 2 + 0] = 0;
    hdr[tid * 2 + 1] = 0;
  }
}

// ---- merged: TWO-PASS pipelined gate (0..255) || W-cast (256..4351) ----
// ROUND-18: merged-kernel LDS cut 69.6KB -> 36.9KB so the 4096 streaming W-cast
// blocks run 4/CU (r16: 2/CU, 1.47 TB/s). Gate GEMM split into two passes over K
// (pass1: W-hi -> acc, xh emit; pass2: W-lo -> accl, A re-staged from L2-hot x),
// each pass = the r16-verified distance-2 pipeline with ONE 32KB B-dbuf;
// per-iter issues {1 x-load + 4 B-loads} -> steady-state vmcnt(5) (same proof).
__global__ __launch_bounds__(256) void gate_cast_kernel(const float* __restrict__ x,
                                                        _Float16* __restrict__ xh,
                                                        const _Float16* __restrict__ WhT,
                                                        const _Float16* __restrict__ WlT,
                                                        const float* __restrict__ Wg2,
                                                        int* __restrict__ top_i,
                                                        float* __restrict__ top_v,
                                                        float* __restrict__ lossacc,
                                                        int* __restrict__ counts,
                                                        int* __restrict__ nflag,
                                                        int* __restrict__ flaglist,
                                                        const float* __restrict__ Win,
                                                        const float* __restrict__ Wout,
                                                        _Float16* __restrict__ WinT,
                                                        _Float16* __restrict__ WoutT) {
  __shared__ __align__(16) char smem[36864];
  int bx = blockIdx.x;
  int tid = threadIdx.x;

  if (bx >= 256) {
    // ---------- W_in / W_out transpose-cast (16640 B of the arena) ----------
    float (*t)[65] = (float(*)[65])smem;
    int b = bx - 256;
    int z = b >> 8, rem = b & 255;
    const float* src = (z < NEXP ? Win : Wout) + (size_t)(z & 7) * DIM * HID;
    _Float16*    dst = (z < NEXP ? WinT : WoutT) + (size_t)(z & 7) * DIM * HID;
    int i0 = (rem & 15) * 64, j0 = (rem >> 4) * 64;
    int col4 = tid & 15, ib = tid >> 4;
#pragma unroll
    for (int q = 0; q < 4; ++q) {
      int i = ib * 4 + q;
      *(float4*)&t[i][col4 * 4] = *(const float4*)&src[(size_t)(i0 + i) * 1024 + j0 + col4 * 4];
    }
    __syncthreads();
#pragma unroll
    for (int q = 0; q < 2; ++q) {
      int c = tid * 2 + q;
      int j = c >> 3, i8 = (c & 7) * 8;
      f16x8 h;
#pragma unroll
      for (int k = 0; k < 8; ++k) h[k] = (_Float16)t[i8 + k][j];
      *(f16x8*)&dst[(size_t)(j0 + j) * 1024 + i0 + i8] = h;
    }
    return;
  }

  // ---------- gate GEMM (32 tokens), two-pass pipelined ----------
  // LDS: Ah[2]@0 (2x2048B), B2[2]@4096 (2x16384B) = 36864 B.
  __shared__ float psum[8];
  __shared__ float entsum;
  __shared__ int cnts[8];
  int m0 = bx * 32;
  int lane = tid & 63, wave = tid >> 6;
  int wr = (wave >> 1) * 16;       // 0 or 16
  int wc = (wave & 1) * 128;       // 0 or 128
  if (tid < 8) { psum[tid] = 0.f; cnts[tid] = 0; }
  if (tid == 0) entsum = 0.f;

  // A staging: row=tid>>3 (0..31), u=tid&7 (4-half unit). Source float col
  // = ((u>>1)^f(row))*8 + (u&1)*4, f(row)=(row>>2)&3 -> 16B-slot invariant kept.
  int arw = tid >> 3, au = tid & 7;
  size_t axbase = (size_t)(m0 + arw) * DIM +
                  (((au >> 1) ^ ((arw >> 2) & 3)) * 8 + (au & 1) * 4);
  int aoff = arw * 32 + au * 4;    // halves
  int srcslot = ((lane & 3) ^ ((lane >> 4) & 3)) << 3;
  size_t bsrc[4];
#pragma unroll
  for (int p = 0; p < 4; ++p)
    bsrc[p] = (size_t)(wave * 16 + p * 64 + (lane >> 2)) * DIM + srcslot;
  int rdoff = ((lane >> 4) ^ ((lane >> 2) & 3)) << 3;
  // xh emit from a-frag: content cols are LINEAR (lane>>4)*8 (swizzles cancel)
  size_t xhoff = (size_t)(m0 + wr + (lane & 15)) * DIM + ((lane >> 4) << 3);
  f32x4 acc[8] = {}, accl[8] = {};
  float4 xv;

#define AH(c) ((_Float16*)(smem + (c) * 2048))
#define B2(c) ((_Float16*)(smem + 4096 + (c) * 16384))
#define CVT_W(dstp)                                            \
  do {                                                         \
    f16x4 h4;                                                  \
    h4[0] = (_Float16)xv.x; h4[1] = (_Float16)xv.y;            \
    h4[2] = (_Float16)xv.z; h4[3] = (_Float16)xv.w;            \
    *(f16x4*)(dstp) = h4;                                      \
  } while (0)
#define ASYNCB4(KK, C, WSRC)                                                 \
  do {                                                                       \
    _Pragma("unroll")                                                        \
    for (int p = 0; p < 4; ++p)                                              \
      async_ld16(WSRC + bsrc[p] + (KK), B2(C) + wave * 512 + p * 2048);      \
  } while (0)

// One full pipelined pass over K with B-source WSRC, accumulator ACCARR.
// Prologue: A(0),A(1) sync; B(0)->b0 (4); issue x(2) (1); B(1)->b1 (4);
// vmcnt(5) drains B(0) (x(2)+B(1)=5 outstanding). Loop invariant: at iter v
// entry, outstanding = x(v+2)+B(v+1)=5; CVT_W waits x(v+2) (compiler); issue
// x(v+3)+B(v+2) -> 9; vmcnt(5) drains B(v+1). Tail v>=30: vmcnt(0).
#define GATE_PASS(WSRC, ACCARR, EMIT)                                        \
  do {                                                                       \
    xv = *(const float4*)(x + axbase);                                       \
    CVT_W(AH(0) + aoff);                                                     \
    xv = *(const float4*)(x + axbase + 32);                                  \
    CVT_W(AH(1) + aoff);                                                     \
    __builtin_amdgcn_sched_barrier(0);                                       \
    ASYNCB4(0, 0, WSRC);                                                     \
    __builtin_amdgcn_sched_barrier(0);                                       \
    xv = *(const float4*)(x + axbase + 64);                                  \
    __builtin_amdgcn_sched_barrier(0);                                       \
    ASYNCB4(32, 1, WSRC);                                                    \
    asm volatile("s_waitcnt vmcnt(5)" ::: "memory");                         \
    asm volatile("s_waitcnt lgkmcnt(0)" ::: "memory");                       \
    __builtin_amdgcn_sched_barrier(0);                                       \
    __builtin_amdgcn_s_barrier();                                            \
    for (int v = 0; v < 32; ++v) {                                           \
      int cb = v & 1;                                                        \
      _Float16* Ah = AH(cb);                                                 \
      _Float16* Bb = B2(cb);                                                 \
      f16x8 a = *(const f16x8*)&Ah[(wr + (lane & 15)) * 32 + rdoff];         \
      f16x8 bfr[8];                                                          \
      _Pragma("unroll")                                                      \
      for (int n = 0; n < 8; ++n)                                            \
        bfr[n] = *(const f16x8*)&Bb[(wc + n * 16 + (lane & 15)) * 32 + rdoff]; \
      if (EMIT) *(f16x8*)(xh + xhoff + (size_t)v * 32) = a;                  \
      asm volatile("s_waitcnt lgkmcnt(0)" ::: "memory");                     \
      __builtin_amdgcn_sched_barrier(0);                                     \
      __builtin_amdgcn_s_barrier();                                          \
      if (v < 30) {                                                          \
        CVT_W(Ah + aoff);                                                    \
        __builtin_amdgcn_sched_barrier(0);                                   \
        int kk = (v + 3 < 32 ? v + 3 : 31) * 32;                             \
        xv = *(const float4*)(x + axbase + kk);                              \
        __builtin_amdgcn_sched_barrier(0);                                   \
        ASYNCB4((v + 2) * 32, cb, WSRC);                                     \
      }                                                                      \
      __builtin_amdgcn_s_setprio(1);                                         \
      _Pragma("unroll")                                                      \
      for (int n = 0; n < 8; ++n)                                            \
        ACCARR[n] = __builtin_amdgcn_mfma_f32_16x16x32_f16(a, bfr[n], ACCARR[n], 0, 0, 0); \
      __builtin_amdgcn_s_setprio(0);                                         \
      if (v < 30) asm volatile("s_waitcnt vmcnt(5)" ::: "memory");           \
      else        asm volatile("s_waitcnt vmcnt(0)" ::: "memory");           \
      asm volatile("s_waitcnt lgkmcnt(0)" ::: "memory");                     \
      __builtin_amdgcn_sched_barrier(0);                                     \
      __builtin_amdgcn_s_barrier();                                          \
    }                                                                        \
  } while (0)

  GATE_PASS(WhT, acc, 1);   // hi pass: emits xh
  GATE_PASS(WlT, accl, 0);  // lo pass: A re-staged (x rows L2-hot)

#undef AH
#undef B2
#undef CVT_W
#undef ASYNCB4
#undef GATE_PASS

  // ---- tanh -> hsm (overlay), then gate ----
  float (*hsm)[260] = (float(*)[260])smem;   // 33280 B overlay (all LDS reads done)
#pragma unroll
  for (int n = 0; n < 8; ++n) {
#pragma unroll
    for (int i = 0; i < 4; ++i) {
      int row = wr + ((lane >> 4) << 2) + i;
      int col = wc + n * 16 + (lane & 15);
      hsm[row][col] = tanhf(acc[n][i] + accl[n][i] * (1.0f / SPLIT_SCALE));
    }
  }
  __syncthreads();

  int tok = tid >> 3, sl = tid & 7;
  float lg[8] = {0, 0, 0, 0, 0, 0, 0, 0};
#pragma unroll
  for (int j = 0; j < 32; ++j) {
    int g = sl + j * 8;
    float hv = hsm[tok][g];
#pragma unroll
    for (int e = 0; e < 8; ++e) lg[e] = fmaf(hv, Wg2[g * 8 + e], lg[e]);
  }
#pragma unroll
  for (int e = 0; e < 8; ++e) {
    lg[e] += __shfl_xor(lg[e], 4);
    lg[e] += __shfl_xor(lg[e], 2);
    lg[e] += __shfl_xor(lg[e], 1);
  }
  if (sl == 0) {
    int token = m0 + tok;
    float mx = lg[0];
#pragma unroll
    for (int e = 1; e < 8; ++e) mx = fmaxf(mx, lg[e]);
    float p[8], s = 0.f;
#pragma unroll
    for (int e = 0; e < 8; ++e) { p[e] = expf(lg[e] - mx); s += p[e]; }
    float inv = 1.f / s, ent = 0.f;
    int i0 = 0, i1 = 0;
    float v0 = -1.f, v1 = -1.f, v2 = -1.f;
#pragma unroll
    for (int e = 0; e < 8; ++e) {
      p[e] *= inv;
      ent += p[e] * logf(p[e] + 1e-9f);
      if (p[e] > v0)      { v2 = v1; v1 = v0; i1 = i0; v0 = p[e]; i0 = e; }
      else if (p[e] > v1) { v2 = v1; v1 = p[e]; i1 = e; }
      else if (p[e] > v2) { v2 = p[e]; }
    }
    top_i[token * 2 + 0] = i0; top_i[token * 2 + 1] = i1;
    top_v[token * 2 + 0] = v0; top_v[token * 2 + 1] = v1;
    if (v1 - v2 < GAP_P) {
      int ix = atomicAdd(nflag, 1);
      if (ix < 8192) flaglist[ix] = token;
    }
#pragma unroll
    for (int e = 0; e < 8; ++e) atomicAdd(&psum[e], p[e]);
    atomicAdd(&entsum, ent);
    atomicAdd(&cnts[i0], 1);
    atomicAdd(&cnts[i1], 1);
  }
  __syncthreads();
  if (tid < 8) { atomicAdd(&lossacc[tid], psum[tid]); atomicAdd(&counts[tid], cnts[tid]); }
  if (tid == 8) atomicAdd(&lossacc[8], entsum);
}

// ------- regate: exact fp32 gate recompute for flagged tokens (parallel) -------
__global__ __launch_bounds__(256) void regate_kernel(const float* __restrict__ x,
                                                     const float* __restrict__ Wg1,
                                                     const float* __restrict__ Wg2,
                                                     const int* __restrict__ nflag,
                                                     const int* __restrict__ flaglist,
                                                     int* __restrict__ top_i,
                                                     float* __restrict__ top_v,
                                                     int* __restrict__ counts) {
  __shared__ float xs[DIM];
  __shared__ float wsum[4][8];
  int tid = threadIdx.x;
  int nf = *nflag; if (nf > 8192) nf = 8192;
  for (int it = blockIdx.x; it < nf; it += gridDim.x) {
    int token = flaglist[it];
    const float* xr = x + (size_t)token * DIM;
    *(float4*)&xs[tid * 4] = *(const float4*)&xr[tid * 4];
    __syncthreads();
    float s0 = 0.f, s1 = 0.f, s2 = 0.f, s3 = 0.f;
    float s4 = 0.f, s5 = 0.f, s6 = 0.f, s7 = 0.f;
    for (int k = 0; k < DIM; k += 8) {
      s0 = fmaf(xs[k + 0], Wg1[(size_t)(k + 0) * GDIM + tid], s0);
      s1 = fmaf(xs[k + 1], Wg1[(size_t)(k + 1) * GDIM + tid], s1);
      s2 = fmaf(xs[k + 2], Wg1[(size_t)(k + 2) * GDIM + tid], s2);
      s3 = fmaf(xs[k + 3], Wg1[(size_t)(k + 3) * GDIM + tid], s3);
      s4 = fmaf(xs[k + 4], Wg1[(size_t)(k + 4) * GDIM + tid], s4);
      s5 = fmaf(xs[k + 5], Wg1[(size_t)(k + 5) * GDIM + tid], s5);
      s6 = fmaf(xs[k + 6], Wg1[(size_t)(k + 6) * GDIM + tid], s6);
      s7 = fmaf(xs[k + 7], Wg1[(size_t)(k + 7) * GDIM + tid], s7);
    }
    float hgv = tanhf(((s0 + s1) + (s2 + s3)) + ((s4 + s5) + (s6 + s7)));
    float lg[8];
#pragma unroll
    for (int e = 0; e < 8; ++e) lg[e] = hgv * Wg2[tid * 8 + e];
#pragma unroll
    for (int e = 0; e < 8; ++e) {
      lg[e] += __shfl_xor(lg[e], 32);
      lg[e] += __shfl_xor(lg[e], 16);
      lg[e] += __shfl_xor(lg[e], 8);
      lg[e] += __shfl_xor(lg[e], 4);
      lg[e] += __shfl_xor(lg[e], 2);
      lg[e] += __shfl_xor(lg[e], 1);
    }
    int wv = tid >> 6;
    if ((tid & 63) == 0) {
#pragma unroll
      for (int e = 0; e < 8; ++e) wsum[wv][e] = lg[e];
    }
    __syncthreads();
    if (tid == 0) {
      float l[8];
#pragma unroll
      for (int e = 0; e < 8; ++e)
        l[e] = (wsum[0][e] + wsum[1][e]) + (wsum[2][e] + wsum[3][e]);
      float mx = l[0];
#pragma unroll
      for (int e = 1; e < 8; ++e) mx = fmaxf(mx, l[e]);
      float p[8], s = 0.f;
#pragma unroll
      for (int e = 0; e < 8; ++e) { p[e] = expf(l[e] - mx); s += p[e]; }
      float inv = 1.f / s;
      int i0 = 0, i1 = 0;
      float v0 = -1.f, v1 = -1.f;
#pragma unroll
      for (int e = 0; e < 8; ++e) {
        p[e] *= inv;
        if (p[e] > v0)      { v1 = v0; i1 = i0; v0 = p[e]; i0 = e; }
        else if (p[e] > v1) { v1 = p[e]; i1 = e; }
      }
      int oi0 = top_i[token * 2 + 0], oi1 = top_i[token * 2 + 1];
      if (oi0 != i0 || oi1 != i1) {
        atomicSub(&counts[oi0], 1); atomicSub(&counts[oi1], 1);
        atomicAdd(&counts[i0], 1);  atomicAdd(&counts[i1], 1);
      }
      top_i[token * 2 + 0] = i0; top_i[token * 2 + 1] = i1;
      top_v[token * 2 + 0] = v0; top_v[token * 2 + 1] = v1;
    }
    __syncthreads();
  }
}

// ------- fill: packed per-expert lists, hierarchical atomics, inline prefix-scan -------
__global__ __launch_bounds__(256) void fill_kernel(const int* __restrict__ top_i,
                                                   const float* __restrict__ top_v,
                                                   const int* __restrict__ counts,
                                                   int* __restrict__ cursors,
                                                   int* __restrict__ ptok,
                                                   float* __restrict__ pgate,
                                                   int* __restrict__ rowof) {
  __shared__ int lcnt[8];
  __shared__ int lbase[8];
  __shared__ int soff[8];
  int tid = threadIdx.x;
  int n = blockIdx.x * 256 + tid;
  if (tid == 0) {
    int a = 0;
#pragma unroll
    for (int e = 0; e < 8; ++e) { soff[e] = a; a += counts[e]; }
  }
  if (tid < 8) lcnt[tid] = 0;
  __syncthreads();
  int e0 = top_i[n * 2 + 0], e1 = top_i[n * 2 + 1];
  int p0 = atomicAdd(&lcnt[e0], 1);
  int p1 = atomicAdd(&lcnt[e1], 1);
  __syncthreads();
  if (tid < 8) lbase[tid] = atomicAdd(&cursors[tid], lcnt[tid]);
  __syncthreads();
  int r0 = soff[e0] + lbase[e0] + p0;
  int r1 = soff[e1] + lbase[e1] + p1;
  ptok[r0] = n;  pgate[r0] = top_v[n * 2 + 0];  rowof[n * 2 + 0] = r0;
  ptok[r1] = n;  pgate[r1] = top_v[n * 2 + 1];  rowof[n * 2 + 1] = r1;
}

// ======== grouped GEMMs: ROUND-8 config verbatim (best measured: 65.1/65.2 us) ========
#define GEMM_PIPE(STAGE_EXPR)                                                        \
  STAGE_EXPR(0, 0);                                                                  \
  STAGE_EXPR(32, 1);                                                                 \
  asm volatile("s_waitcnt vmcnt(3)" ::: "memory");                                   \
  __builtin_amdgcn_s_barrier();                                                      \
  int cbuf = 0;                                                                      \
  for (int t = 0; t < 32; ++t) {                                                     \
    f16x8 a[4], b[4];                                                                \
    _Pragma("unroll")                                                                \
    for (int m = 0; m < 4; ++m)                                                      \
      a[m] = *(const f16x8*)&Als[cbuf][(wr + m * 16 + (lane & 15)) * 32 + rdoff];    \
    _Pragma("unroll")                                                                \
    for (int n = 0; n < 4; ++n)                                                      \
      b[n] = *(const f16x8*)&Bls[cbuf][(wc + n * 16 + (lane & 15)) * 32 + rdoff];    \
    asm volatile("s_waitcnt lgkmcnt(0)" ::: "memory");                               \
    __builtin_amdgcn_sched_barrier(0);                                               \
    __builtin_amdgcn_s_barrier();                                                    \
    bool st = (t + 2 < 32);                                                          \
    if (st) { STAGE_EXPR((t + 2) * 32, cbuf); }                                      \
    __builtin_amdgcn_s_setprio(1);                                                   \
    _Pragma("unroll")                                                                \
    for (int m = 0; m < 4; ++m)                                                      \
      _Pragma("unroll")                                                              \
      for (int n = 0; n < 4; ++n)                                                    \
        acc[m][n] = __builtin_amdgcn_mfma_f32_16x16x32_f16(a[m], b[n], acc[m][n], 0, 0, 0); \
    __builtin_amdgcn_s_setprio(0);                                                   \
    if (st) asm volatile("s_waitcnt vmcnt(3)" ::: "memory");                         \
    else    asm volatile("s_waitcnt vmcnt(0)" ::: "memory");                         \
    __builtin_amdgcn_sched_barrier(0);                                               \
    __builtin_amdgcn_s_barrier();                                                    \
    cbuf ^= 1;                                                                       \
  }

// ---------------- grouped GEMM1: hb[r][h] = relu(x[tok_r] @ W_in[e]) ----------------
__global__ __launch_bounds__(512) void gemm1_kernel(const _Float16* __restrict__ xh,
                                                    const _Float16* __restrict__ WinT,
                                                    _Float16* __restrict__ hb,
                                                    const int* __restrict__ counts,
                                                    const int* __restrict__ ptok) {
  __shared__ __align__(16) _Float16 Als[2][256 * 32];
  __shared__ __align__(16) _Float16 Bls[2][128 * 32];
  int bx = blockIdx.x;
  int loc = (bx & 7) * 9 + (bx >> 3);   // XCD-aware bijective swizzle (72 = 8*9)
  int base = 0, cnt = 0, e;
  for (e = 0; e < NEXP; ++e) {
    cnt = counts[e];
    int mts = (cnt + 255) >> 8;
    if (loc < mts) break;
    loc -= mts; base += cnt;
  }
  if (e == NEXP) return;
  int row0 = base + (loc << 8);
  int rmax = cnt - (loc << 8);
  int n0 = blockIdx.y << 7;
  int tid = threadIdx.x, wave = tid >> 6, lane = tid & 63;
  int wr = (wave >> 1) << 6, wc = (wave & 1) << 6;

  const _Float16* WB = WinT + (size_t)e * DIM * HID;
  int scol = (((lane & 3) ^ (lane >> 4)) << 3);
  size_t asrc[2];
#pragma unroll
  for (int j = 0; j < 2; ++j) {
    int r = wave * 32 + j * 16 + (lane >> 2);
    int tok = ptok[(r < rmax) ? (row0 + r) : base];
    asrc[j] = (size_t)tok * DIM + scol;
  }
  int brow = tid >> 2;
  size_t bsrc = (size_t)(n0 + brow) * DIM + (((tid & 3) ^ ((tid >> 4) & 3)) << 3);
  int aldst = wave * 1024;
  int bldst = wave * 512;
  int rdoff = ((lane >> 4) ^ ((lane >> 2) & 3)) << 3;
  f32x4 acc[4][4] = {};

#define STAGE1(K0, CB)                                          \
  do {                                                          \
    async_ld16(xh + asrc[0] + (K0), &Als[(CB)][aldst]);         \
    async_ld16(xh + asrc[1] + (K0), &Als[(CB)][aldst + 512]);   \
    async_ld16(WB + bsrc + (K0), &Bls[(CB)][bldst]);            \
  } while (0)

  GEMM_PIPE(STAGE1)
#undef STAGE1

#pragma unroll
  for (int m = 0; m < 4; ++m) {
#pragma unroll
    for (int i = 0; i < 4; ++i) {
      int r = wr + m * 16 + ((lane >> 4) << 2) + i;
      if (r < rmax) {
        _Float16* hrow = hb + (size_t)(row0 + r) * HID;
#pragma unroll
        for (int n = 0; n < 4; ++n)
          hrow[n0 + wc + n * 16 + (lane & 15)] = (_Float16)fmaxf(acc[m][n][i], 0.f);
      }
    }
  }
}

// ---------------- grouped GEMM2: yb[r][d] = gate_r * (hb[r] @ W_out[e]) ----------------
__global__ __launch_bounds__(512) void gemm2_kernel(const _Float16* __restrict__ hb,
                                                    const _Float16* __restrict__ WoutT,
                                                    _Float16* __restrict__ yb,
                                                    const int* __restrict__ counts,
                                                    const float* __restrict__ pgate) {
  __shared__ __align__(16) _Float16 Als[2][256 * 32];
  __shared__ __align__(16) _Float16 Bls[2][128 * 32];
  int bx = blockIdx.x;
  int loc = (bx & 7) * 9 + (bx >> 3);
  int base = 0, cnt = 0, e;
  for (e = 0; e < NEXP; ++e) {
    cnt = counts[e];
    int mts = (cnt + 255) >> 8;
    if (loc < mts) break;
    loc -= mts; base += cnt;
  }
  if (e == NEXP) return;
  int row0 = base + (loc << 8);
  int rmax = cnt - (loc << 8);
  int n0 = blockIdx.y << 7;
  int tid = threadIdx.x, wave = tid >> 6, lane = tid & 63;
  int wr = (wave >> 1) << 6, wc = (wave & 1) << 6;

  const _Float16* WB = WoutT + (size_t)e * DIM * HID;
  int scol = (((lane & 3) ^ (lane >> 4)) << 3);
  size_t asrc[2];
#pragma unroll
  for (int j = 0; j < 2; ++j) {
    int r = wave * 32 + j * 16 + (lane >> 2);
    asrc[j] = (size_t)(row0 + r) * HID + scol;   // hb has +256 rows slack: in-bounds
  }
  int brow = tid >> 2;
  size_t bsrc = (size_t)(n0 + brow) * DIM + (((tid & 3) ^ ((tid >> 4) & 3)) << 3);
  int aldst = wave * 1024;
  int bldst = wave * 512;
  int rdoff = ((lane >> 4) ^ ((lane >> 2) & 3)) << 3;
  f32x4 acc[4][4] = {};

#define STAGE2(K0, CB)                                          \
  do {                                                          \
    async_ld16(hb + asrc[0] + (K0), &Als[(CB)][aldst]);         \
    async_ld16(hb + asrc[1] + (K0), &Als[(CB)][aldst + 512]);   \
    async_ld16(WB + bsrc + (K0), &Bls[(CB)][bldst]);            \
  } while (0)

  GEMM_PIPE(STAGE2)
#undef STAGE2

#pragma unroll
  for (int m = 0; m < 4; ++m) {
#pragma unroll
    for (int i = 0; i < 4; ++i) {
      int r = wr + m * 16 + ((lane >> 4) << 2) + i;
      if (r < rmax) {
        int gr = row0 + r;
        float gv = pgate[gr];
        _Float16* yrow = yb + (size_t)gr * DIM;
#pragma unroll
        for (int n = 0; n < 4; ++n)
          yrow[n0 + wc + n * 16 + (lane & 15)] = (_Float16)(gv * acc[m][n][i]);
      }
    }
  }
}

// ---------------- combine: out[n] = yb[rowof[2n]] + yb[rowof[2n+1]]; +loss in block 0 ----------------
__global__ __launch_bounds__(256) void combine_kernel(const _Float16* __restrict__ yb,
                                                      const int* __restrict__ rowof,
                                                      float* __restrict__ out,
                                                      const float* __restrict__ lossacc,
                                                      float* __restrict__ lossdst) {
  int tid = threadIdx.x;
  int token = blockIdx.x * 2 + (tid >> 7);
  int d0 = (tid & 127) * 8;
  int r0 = rowof[token * 2 + 0];
  int r1 = rowof[token * 2 + 1];
  f16x8 a = *(const f16x8*)&yb[(size_t)r0 * DIM + d0];
  f16x8 b = *(const f16x8*)&yb[(size_t)r1 * DIM + d0];
  float* orow = out + (size_t)token * DIM + d0;
  float4 o0, o1;
  o0.x = (float)a[0] + (float)b[0]; o0.y = (float)a[1] + (float)b[1];
  o0.z = (float)a[2] + (float)b[2]; o0.w = (float)a[3] + (float)b[3];
  o1.x = (float)a[4] + (float)b[4]; o1.y = (float)a[5] + (float)b[5];
  o1.z = (float)a[6] + (float)b[6]; o1.w = (float)a[7] + (float)b[7];
  *(float4*)orow = o0;
  *(float4*)(orow + 4) = o1;
  if (blockIdx.x == 0 && tid == 0) {
    float t1 = 0.f;
#pragma unroll
    for (int e = 0; e < 8; ++e) {
      float pm = lossacc[e] * (1.f / (float)N_TOK);
      t1 += pm * logf(pm + 1e-9f);
    }
    lossdst[0] = t1 - lossacc[8] * (1.f / (float)N_TOK);
  }
}

extern "C" void kernel_launch(void* const* d_in, const int* in_sizes, int n_in,
                              void* d_out, int out_size, void* d_ws, size_t ws_size,
                              hipStream_t stream) {
  const float* x    = (const float*)d_in[0];
  const float* Wg1  = (const float*)d_in[1];
  const float* Wg2  = (const float*)d_in[2];
  const float* Win  = (const float*)d_in[3];
  const float* Wout = (const float*)d_in[4];
  float* out = (float*)d_out;

  char* ws = (char*)d_ws;
  size_t off = 0;
  auto alloc = [&](size_t bytes) -> void* {
    void* p = ws + off;
    off = (off + bytes + 255) & ~(size_t)255;
    return p;
  };
  int*   counts  = (int*)alloc(32);    // @0
  int*   cursors = (int*)alloc(32);    // @256
  float* lossacc = (float*)alloc(64);  // @512
  int*   nflag   = (int*)alloc(32);    // @768 -> header [0,800); prep1 zeroes 2048
  int*   flaglist= (int*)alloc(8192 * 4);
  int*   top_i   = (int*)alloc((size_t)NPAIR * 4);
  float* top_v   = (float*)alloc((size_t)NPAIR * 4);
  int*   ptok    = (int*)alloc((size_t)NPAIR * 4);
  float* pgate   = (float*)alloc((size_t)NPAIR * 4);
  int*   rowof   = (int*)alloc((size_t)NPAIR * 4);
  // scratch1: Wg1hT + Wg1lsT live only through gate_cast; then reused as hb.
  char*  scratch1 = (char*)alloc((size_t)HB_ROWS * HID * 2);
  _Float16* Wg1hT  = (_Float16*)scratch1;
  _Float16* Wg1lsT = Wg1hT + (size_t)GDIM * DIM;
  _Float16* hb     = (_Float16*)scratch1;
  _Float16* xh    = (_Float16*)alloc((size_t)N_TOK * DIM * 2);
  _Float16* WinT  = (_Float16*)alloc((size_t)NEXP * DIM * HID * 2);
  _Float16* WoutT = (_Float16*)alloc((size_t)NEXP * DIM * HID * 2);
  // yb[NPAIR][DIM] fp16 (33.5 MB) aliases xh+WinT (both dead by gemm2).
  _Float16* yb = xh;
  (void)ws_size; (void)in_sizes; (void)n_in;

  prep1_kernel<<<65, 256, 0, stream>>>(Wg1, Wg1hT, Wg1lsT, (int*)d_ws);
  gate_cast_kernel<<<256 + 4096, 256, 0, stream>>>(x, xh, Wg1hT, Wg1lsT, Wg2,
                                                   top_i, top_v, lossacc, counts,
                                                   nflag, flaglist,
                                                   Win, Wout, WinT, WoutT);
  regate_kernel<<<256, 256, 0, stream>>>(x, Wg1, Wg2, nflag, flaglist, top_i, top_v, counts);
  fill_kernel<<<N_TOK / 256, 256, 0, stream>>>(top_i, top_v, counts, cursors,
                                               ptok, pgate, rowof);
  gemm1_kernel<<<dim3(MT2, HID / 128), 512, 0, stream>>>(xh, WinT, hb, counts, ptok);
  gemm2_kernel<<<dim3(MT2, DIM / 128), 512, 0, stream>>>(hb, WoutT, yb, counts, pgate);
  combine_kernel<<<N_TOK / 2, 256, 0, stream>>>(yb, rowof, out, lossacc,
                                                out + (size_t)N_TOK * DIM);
}

// Round 19
// 240.058 us; speedup vs baseline: 1.0451x; 1.0451x over previous
//
#include <hip/hip_runtime.h>

// MoE top-2 of 8 experts. B=4,S=2048,D=1024,H=1024,E=8,G=256. N=8192 tokens.
// Outputs: out[8192][1024] fp32, then loss scalar (out_size = 8388609).
// ROUND-19: revert to round-16 verbatim (best measured: 240.2 us).

#define N_TOK 8192
#define DIM   1024
#define HID   1024
#define NEXP  8
#define GDIM  256
#define NPAIR (N_TOK * 2)
#define HB_ROWS (NPAIR + 256)   // packed pair rows + read-slack (tiles read <=255 past end)
#define MT2   72                // >= sum_e ceil(cnt_e/256); 72 = 8*9
#define GAP_P 2e-3f             // xl dropped -> logit err sigma~3e-4; 6-sigma cover
#define SPLIT_SCALE 2048.0f     // W lo-residual scaling

typedef __attribute__((ext_vector_type(4))) float    f32x4;
typedef __attribute__((ext_vector_type(8))) _Float16 f16x8;
typedef __attribute__((ext_vector_type(4))) _Float16 f16x4;

static __device__ __forceinline__ void async_ld16(const void* g, void* l) {
  __builtin_amdgcn_global_load_lds(
      (const __attribute__((address_space(1))) unsigned int*)g,
      (__attribute__((address_space(3))) unsigned int*)l, 16, 0, 0);
}

// ---- prep1: split Wg1^T (hi/lo), zero ws header. 65 blocks (~3 us). ----
__global__ __launch_bounds__(256) void prep1_kernel(const float* __restrict__ Wg1,
                                                    _Float16* __restrict__ WhT,
                                                    _Float16* __restrict__ WlT,
                                                    int* __restrict__ hdr) {
  __shared__ float t[64][65];
  int bx = blockIdx.x;
  int tid = threadIdx.x;
  if (bx < 64) {
    int k0 = (bx & 15) * 64, g0 = (bx >> 4) * 64;
    int col4 = tid & 15, ib = tid >> 4;
#pragma unroll
    for (int q = 0; q < 4; ++q) {
      int i = ib * 4 + q;
      *(float4*)&t[i][col4 * 4] = *(const float4*)&Wg1[(size_t)(k0 + i) * GDIM + g0 + col4 * 4];
    }
    __syncthreads();
#pragma unroll
    for (int q = 0; q < 2; ++q) {
      int c = tid * 2 + q;
      int j = c >> 3, i8 = (c & 7) * 8;
      f16x8 h, l;
#pragma unroll
      for (int k = 0; k < 8; ++k) {
        float v = t[i8 + k][j];
        _Float16 hi = (_Float16)v;
        h[k] = hi;
        l[k] = (_Float16)((v - (float)hi) * SPLIT_SCALE);
      }
      *(f16x8*)&WhT[(size_t)(g0 + j) * DIM + k0 + i8] = h;
      *(f16x8*)&WlT[(size_t)(g0 + j) * DIM + k0 + i8] = l;
    }
  } else {
    hdr[tid * 2 + 0] = 0;
    hdr[tid * 2 + 1] = 0;
  }
}

// ---- merged launch: PIPELINED gate GEMM+gate+xh-emit (0..255) || W-cast (256..4351) ----
__global__ __launch_bounds__(256) void gate_cast_kernel(const float* __restrict__ x,
                                                        _Float16* __restrict__ xh,
                                                        const _Float16* __restrict__ WhT,
                                                        const _Float16* __restrict__ WlT,
                                                        const float* __restrict__ Wg2,
                                                        int* __restrict__ top_i,
                                                        float* __restrict__ top_v,
                                                        float* __restrict__ lossacc,
                                                        int* __restrict__ counts,
                                                        int* __restrict__ nflag,
                                                        int* __restrict__ flaglist,
                                                        const float* __restrict__ Win,
                                                        const float* __restrict__ Wout,
                                                        _Float16* __restrict__ WinT,
                                                        _Float16* __restrict__ WoutT) {
  __shared__ __align__(16) char smem[69632];
  int bx = blockIdx.x;
  int tid = threadIdx.x;

  if (bx >= 256) {
    // ---------- W_in / W_out transpose-cast (uses first 16640 B) ----------
    float (*t)[65] = (float(*)[65])smem;
    int b = bx - 256;
    int z = b >> 8, rem = b & 255;
    const float* src = (z < NEXP ? Win : Wout) + (size_t)(z & 7) * DIM * HID;
    _Float16*    dst = (z < NEXP ? WinT : WoutT) + (size_t)(z & 7) * DIM * HID;
    int i0 = (rem & 15) * 64, j0 = (rem >> 4) * 64;
    int col4 = tid & 15, ib = tid >> 4;
#pragma unroll
    for (int q = 0; q < 4; ++q) {
      int i = ib * 4 + q;
      *(float4*)&t[i][col4 * 4] = *(const float4*)&src[(size_t)(i0 + i) * 1024 + j0 + col4 * 4];
    }
    __syncthreads();
#pragma unroll
    for (int q = 0; q < 2; ++q) {
      int c = tid * 2 + q;
      int j = c >> 3, i8 = (c & 7) * 8;
      f16x8 h;
#pragma unroll
      for (int k = 0; k < 8; ++k) h[k] = (_Float16)t[i8 + k][j];
      *(f16x8*)&dst[(size_t)(j0 + j) * 1024 + i0 + i8] = h;
    }
    return;
  }

  // ---------- gate GEMM (32 tokens), pipelined ----------
  // LDS: Ah[2]@0 (2x2048B), Bh[2]@4096 (2x16384), Bl[2]@36864 (2x16384) = 69632B
  __shared__ float psum[8];
  __shared__ float entsum;
  __shared__ int cnts[8];
  int m0 = bx * 32;
  int lane = tid & 63, wave = tid >> 6;
  int wr = (wave >> 1) * 16;       // 0 or 16
  int wc = (wave & 1) * 128;       // 0 or 128
  if (tid < 8) { psum[tid] = 0.f; cnts[tid] = 0; }
  if (tid == 0) entsum = 0.f;

  // A staging: row=tid>>3 (0..31), u=tid&7 (4-half unit). Source float col
  // = ((u>>1)^f(row))*8 + (u&1)*4, f(row)=(row>>2)&3 -> 16B-slot invariant kept.
  int arw = tid >> 3, au = tid & 7;
  size_t axbase = (size_t)(m0 + arw) * DIM +
                  (((au >> 1) ^ ((arw >> 2) & 3)) * 8 + (au & 1) * 4);
  int aoff = arw * 32 + au * 4;    // halves
  int srcslot = ((lane & 3) ^ ((lane >> 4) & 3)) << 3;
  size_t bsrc[4];
#pragma unroll
  for (int p = 0; p < 4; ++p)
    bsrc[p] = (size_t)(wave * 16 + p * 64 + (lane >> 2)) * DIM + srcslot;
  int rdoff = ((lane >> 4) ^ ((lane >> 2) & 3)) << 3;
  // xh emit from a-frag: content cols are LINEAR (lane>>4)*8 (swizzles cancel)
  size_t xhoff = (size_t)(m0 + wr + (lane & 15)) * DIM + ((lane >> 4) << 3);
  f32x4 acc[8] = {}, accl[8] = {};
  float4 xv;

#define AH(c) ((_Float16*)(smem + (c) * 2048))
#define BH(c) ((_Float16*)(smem + 4096 + (c) * 16384))
#define BL(c) ((_Float16*)(smem + 36864 + (c) * 16384))
#define CVT_W(dstp)                                            \
  do {                                                         \
    f16x4 h4;                                                  \
    h4[0] = (_Float16)xv.x; h4[1] = (_Float16)xv.y;            \
    h4[2] = (_Float16)xv.z; h4[3] = (_Float16)xv.w;            \
    *(f16x4*)(dstp) = h4;                                      \
  } while (0)
#define ASYNCB(KK, C)                                                        \
  do {                                                                       \
    _Pragma("unroll")                                                        \
    for (int p = 0; p < 4; ++p) {                                            \
      async_ld16(WhT + bsrc[p] + (KK), BH(C) + wave * 512 + p * 2048);       \
      async_ld16(WlT + bsrc[p] + (KK), BL(C) + wave * 512 + p * 2048);       \
    }                                                                        \
  } while (0)

  // ---- prologue: A(0),A(1) sync; B(0)->b0; issue x(2); B(1)->b1 ----
  xv = *(const float4*)(x + axbase);
  CVT_W(AH(0) + aoff);
  xv = *(const float4*)(x + axbase + 32);
  CVT_W(AH(1) + aoff);
  __builtin_amdgcn_sched_barrier(0);
  ASYNCB(0, 0);
  __builtin_amdgcn_sched_barrier(0);
  xv = *(const float4*)(x + axbase + 64);   // issue x(2)
  __builtin_amdgcn_sched_barrier(0);
  ASYNCB(32, 1);
  asm volatile("s_waitcnt vmcnt(9)" ::: "memory");   // B(0) drained (x(2)+B(1) allowed)
  asm volatile("s_waitcnt lgkmcnt(0)" ::: "memory"); // A writes drained
  __builtin_amdgcn_sched_barrier(0);
  __builtin_amdgcn_s_barrier();

  for (int v = 0; v < 32; ++v) {
    int cb = v & 1;
    _Float16* Ah = AH(cb);
    _Float16* Bh = BH(cb);
    _Float16* Bl = BL(cb);
    f16x8 a = *(const f16x8*)&Ah[(wr + (lane & 15)) * 32 + rdoff];
    f16x8 bh[8], bl[8];
#pragma unroll
    for (int n = 0; n < 8; ++n) {
      bh[n] = *(const f16x8*)&Bh[(wc + n * 16 + (lane & 15)) * 32 + rdoff];
      bl[n] = *(const f16x8*)&Bl[(wc + n * 16 + (lane & 15)) * 32 + rdoff];
    }
    *(f16x8*)(xh + xhoff + (size_t)v * 32) = a;   // xh emit (dup across wave pairs, benign)
    asm volatile("s_waitcnt lgkmcnt(0)" ::: "memory");
    __builtin_amdgcn_sched_barrier(0);
    __builtin_amdgcn_s_barrier();
    if (v < 30) {
      CVT_W(Ah + aoff);                            // A(v+2); compiler waits xv's loads
      __builtin_amdgcn_sched_barrier(0);
      int kk = (v + 3 < 32 ? v + 3 : 31) * 32;     // uniform issue (dummy at v=29)
      xv = *(const float4*)(x + axbase + kk);
      __builtin_amdgcn_sched_barrier(0);
      ASYNCB((v + 2) * 32, cb);
    }
    __builtin_amdgcn_s_setprio(1);
#pragma unroll
    for (int n = 0; n < 8; ++n) {
      acc[n]  = __builtin_amdgcn_mfma_f32_16x16x32_f16(a, bh[n], acc[n], 0, 0, 0);
      accl[n] = __builtin_amdgcn_mfma_f32_16x16x32_f16(a, bl[n], accl[n], 0, 0, 0);
    }
    __builtin_amdgcn_s_setprio(0);
    if (v < 30) asm volatile("s_waitcnt vmcnt(9)" ::: "memory");
    else        asm volatile("s_waitcnt vmcnt(0)" ::: "memory");
    asm volatile("s_waitcnt lgkmcnt(0)" ::: "memory");
    __builtin_amdgcn_sched_barrier(0);
    __builtin_amdgcn_s_barrier();
  }
#undef AH
#undef BH
#undef BL
#undef CVT_W
#undef ASYNCB

  // ---- tanh -> hsm (overlay), then gate ----
  float (*hsm)[260] = (float(*)[260])smem;   // 33280 B overlay (all LDS reads done)
#pragma unroll
  for (int n = 0; n < 8; ++n) {
#pragma unroll
    for (int i = 0; i < 4; ++i) {
      int row = wr + ((lane >> 4) << 2) + i;
      int col = wc + n * 16 + (lane & 15);
      hsm[row][col] = tanhf(acc[n][i] + accl[n][i] * (1.0f / SPLIT_SCALE));
    }
  }
  __syncthreads();

  int tok = tid >> 3, sl = tid & 7;
  float lg[8] = {0, 0, 0, 0, 0, 0, 0, 0};
#pragma unroll
  for (int j = 0; j < 32; ++j) {
    int g = sl + j * 8;
    float hv = hsm[tok][g];
#pragma unroll
    for (int e = 0; e < 8; ++e) lg[e] = fmaf(hv, Wg2[g * 8 + e], lg[e]);
  }
#pragma unroll
  for (int e = 0; e < 8; ++e) {
    lg[e] += __shfl_xor(lg[e], 4);
    lg[e] += __shfl_xor(lg[e], 2);
    lg[e] += __shfl_xor(lg[e], 1);
  }
  if (sl == 0) {
    int token = m0 + tok;
    float mx = lg[0];
#pragma unroll
    for (int e = 1; e < 8; ++e) mx = fmaxf(mx, lg[e]);
    float p[8], s = 0.f;
#pragma unroll
    for (int e = 0; e < 8; ++e) { p[e] = expf(lg[e] - mx); s += p[e]; }
    float inv = 1.f / s, ent = 0.f;
    int i0 = 0, i1 = 0;
    float v0 = -1.f, v1 = -1.f, v2 = -1.f;
#pragma unroll
    for (int e = 0; e < 8; ++e) {
      p[e] *= inv;
      ent += p[e] * logf(p[e] + 1e-9f);
      if (p[e] > v0)      { v2 = v1; v1 = v0; i1 = i0; v0 = p[e]; i0 = e; }
      else if (p[e] > v1) { v2 = v1; v1 = p[e]; i1 = e; }
      else if (p[e] > v2) { v2 = p[e]; }
    }
    top_i[token * 2 + 0] = i0; top_i[token * 2 + 1] = i1;
    top_v[token * 2 + 0] = v0; top_v[token * 2 + 1] = v1;
    if (v1 - v2 < GAP_P) {
      int ix = atomicAdd(nflag, 1);
      if (ix < 8192) flaglist[ix] = token;
    }
#pragma unroll
    for (int e = 0; e < 8; ++e) atomicAdd(&psum[e], p[e]);
    atomicAdd(&entsum, ent);
    atomicAdd(&cnts[i0], 1);
    atomicAdd(&cnts[i1], 1);
  }
  __syncthreads();
  if (tid < 8) { atomicAdd(&lossacc[tid], psum[tid]); atomicAdd(&counts[tid], cnts[tid]); }
  if (tid == 8) atomicAdd(&lossacc[8], entsum);
}

// ------- regate: exact fp32 gate recompute for flagged tokens (parallel) -------
__global__ __launch_bounds__(256) void regate_kernel(const float* __restrict__ x,
                                                     const float* __restrict__ Wg1,
                                                     const float* __restrict__ Wg2,
                                                     const int* __restrict__ nflag,
                                                     const int* __restrict__ flaglist,
                                                     int* __restrict__ top_i,
                                                     float* __restrict__ top_v,
                                                     int* __restrict__ counts) {
  __shared__ float xs[DIM];
  __shared__ float wsum[4][8];
  int tid = threadIdx.x;
  int nf = *nflag; if (nf > 8192) nf = 8192;
  for (int it = blockIdx.x; it < nf; it += gridDim.x) {
    int token = flaglist[it];
    const float* xr = x + (size_t)token * DIM;
    *(float4*)&xs[tid * 4] = *(const float4*)&xr[tid * 4];
    __syncthreads();
    float s0 = 0.f, s1 = 0.f, s2 = 0.f, s3 = 0.f;
    float s4 = 0.f, s5 = 0.f, s6 = 0.f, s7 = 0.f;
    for (int k = 0; k < DIM; k += 8) {
      s0 = fmaf(xs[k + 0], Wg1[(size_t)(k + 0) * GDIM + tid], s0);
      s1 = fmaf(xs[k + 1], Wg1[(size_t)(k + 1) * GDIM + tid], s1);
      s2 = fmaf(xs[k + 2], Wg1[(size_t)(k + 2) * GDIM + tid], s2);
      s3 = fmaf(xs[k + 3], Wg1[(size_t)(k + 3) * GDIM + tid], s3);
      s4 = fmaf(xs[k + 4], Wg1[(size_t)(k + 4) * GDIM + tid], s4);
      s5 = fmaf(xs[k + 5], Wg1[(size_t)(k + 5) * GDIM + tid], s5);
      s6 = fmaf(xs[k + 6], Wg1[(size_t)(k + 6) * GDIM + tid], s6);
      s7 = fmaf(xs[k + 7], Wg1[(size_t)(k + 7) * GDIM + tid], s7);
    }
    float hgv = tanhf(((s0 + s1) + (s2 + s3)) + ((s4 + s5) + (s6 + s7)));
    float lg[8];
#pragma unroll
    for (int e = 0; e < 8; ++e) lg[e] = hgv * Wg2[tid * 8 + e];
#pragma unroll
    for (int e = 0; e < 8; ++e) {
      lg[e] += __shfl_xor(lg[e], 32);
      lg[e] += __shfl_xor(lg[e], 16);
      lg[e] += __shfl_xor(lg[e], 8);
      lg[e] += __shfl_xor(lg[e], 4);
      lg[e] += __shfl_xor(lg[e], 2);
      lg[e] += __shfl_xor(lg[e], 1);
    }
    int wv = tid >> 6;
    if ((tid & 63) == 0) {
#pragma unroll
      for (int e = 0; e < 8; ++e) wsum[wv][e] = lg[e];
    }
    __syncthreads();
    if (tid == 0) {
      float l[8];
#pragma unroll
      for (int e = 0; e < 8; ++e)
        l[e] = (wsum[0][e] + wsum[1][e]) + (wsum[2][e] + wsum[3][e]);
      float mx = l[0];
#pragma unroll
      for (int e = 1; e < 8; ++e) mx = fmaxf(mx, l[e]);
      float p[8], s = 0.f;
#pragma unroll
      for (int e = 0; e < 8; ++e) { p[e] = expf(l[e] - mx); s += p[e]; }
      float inv = 1.f / s;
      int i0 = 0, i1 = 0;
      float v0 = -1.f, v1 = -1.f;
#pragma unroll
      for (int e = 0; e < 8; ++e) {
        p[e] *= inv;
        if (p[e] > v0)      { v1 = v0; i1 = i0; v0 = p[e]; i0 = e; }
        else if (p[e] > v1) { v1 = p[e]; i1 = e; }
      }
      int oi0 = top_i[token * 2 + 0], oi1 = top_i[token * 2 + 1];
      if (oi0 != i0 || oi1 != i1) {
        atomicSub(&counts[oi0], 1); atomicSub(&counts[oi1], 1);
        atomicAdd(&counts[i0], 1);  atomicAdd(&counts[i1], 1);
      }
      top_i[token * 2 + 0] = i0; top_i[token * 2 + 1] = i1;
      top_v[token * 2 + 0] = v0; top_v[token * 2 + 1] = v1;
    }
    __syncthreads();
  }
}

// ------- fill: packed per-expert lists, hierarchical atomics, inline prefix-scan -------
__global__ __launch_bounds__(256) void fill_kernel(const int* __restrict__ top_i,
                                                   const float* __restrict__ top_v,
                                                   const int* __restrict__ counts,
                                                   int* __restrict__ cursors,
                                                   int* __restrict__ ptok,
                                                   float* __restrict__ pgate,
                                                   int* __restrict__ rowof) {
  __shared__ int lcnt[8];
  __shared__ int lbase[8];
  __shared__ int soff[8];
  int tid = threadIdx.x;
  int n = blockIdx.x * 256 + tid;
  if (tid == 0) {
    int a = 0;
#pragma unroll
    for (int e = 0; e < 8; ++e) { soff[e] = a; a += counts[e]; }
  }
  if (tid < 8) lcnt[tid] = 0;
  __syncthreads();
  int e0 = top_i[n * 2 + 0], e1 = top_i[n * 2 + 1];
  int p0 = atomicAdd(&lcnt[e0], 1);
  int p1 = atomicAdd(&lcnt[e1], 1);
  __syncthreads();
  if (tid < 8) lbase[tid] = atomicAdd(&cursors[tid], lcnt[tid]);
  __syncthreads();
  int r0 = soff[e0] + lbase[e0] + p0;
  int r1 = soff[e1] + lbase[e1] + p1;
  ptok[r0] = n;  pgate[r0] = top_v[n * 2 + 0];  rowof[n * 2 + 0] = r0;
  ptok[r1] = n;  pgate[r1] = top_v[n * 2 + 1];  rowof[n * 2 + 1] = r1;
}

// ======== grouped GEMMs: ROUND-8 config verbatim (best measured: 65.1/65.2 us) ========
#define GEMM_PIPE(STAGE_EXPR)                                                        \
  STAGE_EXPR(0, 0);                                                                  \
  STAGE_EXPR(32, 1);                                                                 \
  asm volatile("s_waitcnt vmcnt(3)" ::: "memory");                                   \
  __builtin_amdgcn_s_barrier();                                                      \
  int cbuf = 0;                                                                      \
  for (int t = 0; t < 32; ++t) {                                                     \
    f16x8 a[4], b[4];                                                                \
    _Pragma("unroll")                                                                \
    for (int m = 0; m < 4; ++m)                                                      \
      a[m] = *(const f16x8*)&Als[cbuf][(wr + m * 16 + (lane & 15)) * 32 + rdoff];    \
    _Pragma("unroll")                                                                \
    for (int n = 0; n < 4; ++n)                                                      \
      b[n] = *(const f16x8*)&Bls[cbuf][(wc + n * 16 + (lane & 15)) * 32 + rdoff];    \
    asm volatile("s_waitcnt lgkmcnt(0)" ::: "memory");                               \
    __builtin_amdgcn_sched_barrier(0);                                               \
    __builtin_amdgcn_s_barrier();                                                    \
    bool st = (t + 2 < 32);                                                          \
    if (st) { STAGE_EXPR((t + 2) * 32, cbuf); }                                      \
    __builtin_amdgcn_s_setprio(1);                                                   \
    _Pragma("unroll")                                                                \
    for (int m = 0; m < 4; ++m)                                                      \
      _Pragma("unroll")                                                              \
      for (int n = 0; n < 4; ++n)                                                    \
        acc[m][n] = __builtin_amdgcn_mfma_f32_16x16x32_f16(a[m], b[n], acc[m][n], 0, 0, 0); \
    __builtin_amdgcn_s_setprio(0);                                                   \
    if (st) asm volatile("s_waitcnt vmcnt(3)" ::: "memory");                         \
    else    asm volatile("s_waitcnt vmcnt(0)" ::: "memory");                         \
    __builtin_amdgcn_sched_barrier(0);                                               \
    __builtin_amdgcn_s_barrier();                                                    \
    cbuf ^= 1;                                                                       \
  }

// ---------------- grouped GEMM1: hb[r][h] = relu(x[tok_r] @ W_in[e]) ----------------
__global__ __launch_bounds__(512) void gemm1_kernel(const _Float16* __restrict__ xh,
                                                    const _Float16* __restrict__ WinT,
                                                    _Float16* __restrict__ hb,
                                                    const int* __restrict__ counts,
                                                    const int* __restrict__ ptok) {
  __shared__ __align__(16) _Float16 Als[2][256 * 32];
  __shared__ __align__(16) _Float16 Bls[2][128 * 32];
  int bx = blockIdx.x;
  int loc = (bx & 7) * 9 + (bx >> 3);   // XCD-aware bijective swizzle (72 = 8*9)
  int base = 0, cnt = 0, e;
  for (e = 0; e < NEXP; ++e) {
    cnt = counts[e];
    int mts = (cnt + 255) >> 8;
    if (loc < mts) break;
    loc -= mts; base += cnt;
  }
  if (e == NEXP) return;
  int row0 = base + (loc << 8);
  int rmax = cnt - (loc << 8);
  int n0 = blockIdx.y << 7;
  int tid = threadIdx.x, wave = tid >> 6, lane = tid & 63;
  int wr = (wave >> 1) << 6, wc = (wave & 1) << 6;

  const _Float16* WB = WinT + (size_t)e * DIM * HID;
  int scol = (((lane & 3) ^ (lane >> 4)) << 3);
  size_t asrc[2];
#pragma unroll
  for (int j = 0; j < 2; ++j) {
    int r = wave * 32 + j * 16 + (lane >> 2);
    int tok = ptok[(r < rmax) ? (row0 + r) : base];
    asrc[j] = (size_t)tok * DIM + scol;
  }
  int brow = tid >> 2;
  size_t bsrc = (size_t)(n0 + brow) * DIM + (((tid & 3) ^ ((tid >> 4) & 3)) << 3);
  int aldst = wave * 1024;
  int bldst = wave * 512;
  int rdoff = ((lane >> 4) ^ ((lane >> 2) & 3)) << 3;
  f32x4 acc[4][4] = {};

#define STAGE1(K0, CB)                                          \
  do {                                                          \
    async_ld16(xh + asrc[0] + (K0), &Als[(CB)][aldst]);         \
    async_ld16(xh + asrc[1] + (K0), &Als[(CB)][aldst + 512]);   \
    async_ld16(WB + bsrc + (K0), &Bls[(CB)][bldst]);            \
  } while (0)

  GEMM_PIPE(STAGE1)
#undef STAGE1

#pragma unroll
  for (int m = 0; m < 4; ++m) {
#pragma unroll
    for (int i = 0; i < 4; ++i) {
      int r = wr + m * 16 + ((lane >> 4) << 2) + i;
      if (r < rmax) {
        _Float16* hrow = hb + (size_t)(row0 + r) * HID;
#pragma unroll
        for (int n = 0; n < 4; ++n)
          hrow[n0 + wc + n * 16 + (lane & 15)] = (_Float16)fmaxf(acc[m][n][i], 0.f);
      }
    }
  }
}

// ---------------- grouped GEMM2: yb[r][d] = gate_r * (hb[r] @ W_out[e]) ----------------
__global__ __launch_bounds__(512) void gemm2_kernel(const _Float16* __restrict__ hb,
                                                    const _Float16* __restrict__ WoutT,
                                                    _Float16* __restrict__ yb,
                                                    const int* __restrict__ counts,
                                                    const float* __restrict__ pgate) {
  __shared__ __align__(16) _Float16 Als[2][256 * 32];
  __shared__ __align__(16) _Float16 Bls[2][128 * 32];
  int bx = blockIdx.x;
  int loc = (bx & 7) * 9 + (bx >> 3);
  int base = 0, cnt = 0, e;
  for (e = 0; e < NEXP; ++e) {
    cnt = counts[e];
    int mts = (cnt + 255) >> 8;
    if (loc < mts) break;
    loc -= mts; base += cnt;
  }
  if (e == NEXP) return;
  int row0 = base + (loc << 8);
  int rmax = cnt - (loc << 8);
  int n0 = blockIdx.y << 7;
  int tid = threadIdx.x, wave = tid >> 6, lane = tid & 63;
  int wr = (wave >> 1) << 6, wc = (wave & 1) << 6;

  const _Float16* WB = WoutT + (size_t)e * DIM * HID;
  int scol = (((lane & 3) ^ (lane >> 4)) << 3);
  size_t asrc[2];
#pragma unroll
  for (int j = 0; j < 2; ++j) {
    int r = wave * 32 + j * 16 + (lane >> 2);
    asrc[j] = (size_t)(row0 + r) * HID + scol;   // hb has +256 rows slack: in-bounds
  }
  int brow = tid >> 2;
  size_t bsrc = (size_t)(n0 + brow) * DIM + (((tid & 3) ^ ((tid >> 4) & 3)) << 3);
  int aldst = wave * 1024;
  int bldst = wave * 512;
  int rdoff = ((lane >> 4) ^ ((lane >> 2) & 3)) << 3;
  f32x4 acc[4][4] = {};

#define STAGE2(K0, CB)                                          \
  do {                                                          \
    async_ld16(hb + asrc[0] + (K0), &Als[(CB)][aldst]);         \
    async_ld16(hb + asrc[1] + (K0), &Als[(CB)][aldst + 512]);   \
    async_ld16(WB + bsrc + (K0), &Bls[(CB)][bldst]);            \
  } while (0)

  GEMM_PIPE(STAGE2)
#undef STAGE2

#pragma unroll
  for (int m = 0; m < 4; ++m) {
#pragma unroll
    for (int i = 0; i < 4; ++i) {
      int r = wr + m * 16 + ((lane >> 4) << 2) + i;
      if (r < rmax) {
        int gr = row0 + r;
        float gv = pgate[gr];
        _Float16* yrow = yb + (size_t)gr * DIM;
#pragma unroll
        for (int n = 0; n < 4; ++n)
          yrow[n0 + wc + n * 16 + (lane & 15)] = (_Float16)(gv * acc[m][n][i]);
      }
    }
  }
}

// ---------------- combine: out[n] = yb[rowof[2n]] + yb[rowof[2n+1]]; +loss in block 0 ----------------
__global__ __launch_bounds__(256) void combine_kernel(const _Float16* __restrict__ yb,
                                                      const int* __restrict__ rowof,
                                                      float* __restrict__ out,
                                                      const float* __restrict__ lossacc,
                                                      float* __restrict__ lossdst) {
  int tid = threadIdx.x;
  int token = blockIdx.x * 2 + (tid >> 7);
  int d0 = (tid & 127) * 8;
  int r0 = rowof[token * 2 + 0];
  int r1 = rowof[token * 2 + 1];
  f16x8 a = *(const f16x8*)&yb[(size_t)r0 * DIM + d0];
  f16x8 b = *(const f16x8*)&yb[(size_t)r1 * DIM + d0];
  float* orow = out + (size_t)token * DIM + d0;
  float4 o0, o1;
  o0.x = (float)a[0] + (float)b[0]; o0.y = (float)a[1] + (float)b[1];
  o0.z = (float)a[2] + (float)b[2]; o0.w = (float)a[3] + (float)b[3];
  o1.x = (float)a[4] + (float)b[4]; o1.y = (float)a[5] + (float)b[5];
  o1.z = (float)a[6] + (float)b[6]; o1.w = (float)a[7] + (float)b[7];
  *(float4*)orow = o0;
  *(float4*)(orow + 4) = o1;
  if (blockIdx.x == 0 && tid == 0) {
    float t1 = 0.f;
#pragma unroll
    for (int e = 0; e < 8; ++e) {
      float pm = lossacc[e] * (1.f / (float)N_TOK);
      t1 += pm * logf(pm + 1e-9f);
    }
    lossdst[0] = t1 - lossacc[8] * (1.f / (float)N_TOK);
  }
}

extern "C" void kernel_launch(void* const* d_in, const int* in_sizes, int n_in,
                              void* d_out, int out_size, void* d_ws, size_t ws_size,
                              hipStream_t stream) {
  const float* x    = (const float*)d_in[0];
  const float* Wg1  = (const float*)d_in[1];
  const float* Wg2  = (const float*)d_in[2];
  const float* Win  = (const float*)d_in[3];
  const float* Wout = (const float*)d_in[4];
  float* out = (float*)d_out;

  char* ws = (char*)d_ws;
  size_t off = 0;
  auto alloc = [&](size_t bytes) -> void* {
    void* p = ws + off;
    off = (off + bytes + 255) & ~(size_t)255;
    return p;
  };
  int*   counts  = (int*)alloc(32);    // @0
  int*   cursors = (int*)alloc(32);    // @256
  float* lossacc = (float*)alloc(64);  // @512
  int*   nflag   = (int*)alloc(32);    // @768 -> header [0,800); prep1 zeroes 2048
  int*   flaglist= (int*)alloc(8192 * 4);
  int*   top_i   = (int*)alloc((size_t)NPAIR * 4);
  float* top_v   = (float*)alloc((size_t)NPAIR * 4);
  int*   ptok    = (int*)alloc((size_t)NPAIR * 4);
  float* pgate   = (float*)alloc((size_t)NPAIR * 4);
  int*   rowof   = (int*)alloc((size_t)NPAIR * 4);
  // scratch1: Wg1hT + Wg1lsT live only through gate_cast; then reused as hb.
  char*  scratch1 = (char*)alloc((size_t)HB_ROWS * HID * 2);
  _Float16* Wg1hT  = (_Float16*)scratch1;
  _Float16* Wg1lsT = Wg1hT + (size_t)GDIM * DIM;
  _Float16* hb     = (_Float16*)scratch1;
  _Float16* xh    = (_Float16*)alloc((size_t)N_TOK * DIM * 2);
  _Float16* WinT  = (_Float16*)alloc((size_t)NEXP * DIM * HID * 2);
  _Float16* WoutT = (_Float16*)alloc((size_t)NEXP * DIM * HID * 2);
  // yb[NPAIR][DIM] fp16 (33.5 MB) aliases xh+WinT (both dead by gemm2).
  _Float16* yb = xh;
  (void)ws_size; (void)in_sizes; (void)n_in;

  prep1_kernel<<<65, 256, 0, stream>>>(Wg1, Wg1hT, Wg1lsT, (int*)d_ws);
  gate_cast_kernel<<<256 + 4096, 256, 0, stream>>>(x, xh, Wg1hT, Wg1lsT, Wg2,
                                                   top_i, top_v, lossacc, counts,
                                                   nflag, flaglist,
                                                   Win, Wout, WinT, WoutT);
  regate_kernel<<<256, 256, 0, stream>>>(x, Wg1, Wg2, nflag, flaglist, top_i, top_v, counts);
  fill_kernel<<<N_TOK / 256, 256, 0, stream>>>(top_i, top_v, counts, cursors,
                                               ptok, pgate, rowof);
  gemm1_kernel<<<dim3(MT2, HID / 128), 512, 0, stream>>>(xh, WinT, hb, counts, ptok);
  gemm2_kernel<<<dim3(MT2, DIM / 128), 512, 0, stream>>>(hb, WoutT, yb, counts, pgate);
  combine_kernel<<<N_TOK / 2, 256, 0, stream>>>(yb, rowof, out, lossacc,
                                                out + (size_t)N_TOK * DIM);
}